// Round 10
// baseline (47.696 us; speedup 1.0000x reference)
//
#include <hip/hip_runtime.h>
#include <math.h>

#define HW 16384
#define NPROJ 100
#define NB 8
#define NCH 32
#define CHLEN 512
#define EPSV 1e-6f

// Stage 1: per-(batch, chunk) partials: Xs = x0+x1+x2 (stored), sum(Xs), sum(y0),
// chunk max/argmax of x0 (first-occurrence). Block 0 zeroes the output.
__global__ __launch_bounds__(256) void partial_kernel(const float* __restrict__ X,
                                                      const float* __restrict__ Y,
                                                      float* __restrict__ Xs,
                                                      float* __restrict__ Pmax,
                                                      int* __restrict__ Pidx,
                                                      float* __restrict__ Psx,
                                                      float* __restrict__ Psy,
                                                      float* __restrict__ out) {
    const int blk = blockIdx.x;
    const int b = blk >> 5, c = blk & 31;
    const int tid = threadIdx.x, lane = tid & 63, wid = tid >> 6;
    if (blk == 0 && tid == 0) out[0] = 0.0f;  // consumed only by wproj (later kernel)
    const float* xb = X + (size_t)b * 3 * HW;
    const float* yb = Y + (size_t)b * 3 * HW;
    const int base = c * CHLEN;

    float mv = -INFINITY;
    int mi = 0;
    float sx = 0.0f, sy = 0.0f;
#pragma unroll
    for (int k = 0; k < 2; ++k) {
        int p = base + k * 256 + tid;
        float x0 = xb[p], x1 = xb[HW + p], x2 = xb[2 * HW + p], y0 = yb[p];
        float s = x0 + x1 + x2;
        Xs[(size_t)b * HW + p] = s;
        sx += s;
        sy += y0;
        if (x0 > mv) { mv = x0; mi = p; }   // strict > keeps earliest p
    }
#pragma unroll
    for (int off = 32; off > 0; off >>= 1) {
        float ov = __shfl_down(mv, off);
        int oi = __shfl_down(mi, off);
        sx += __shfl_down(sx, off);
        sy += __shfl_down(sy, off);
        if (ov > mv || (ov == mv && oi < mi)) { mv = ov; mi = oi; }
    }
    __shared__ float lmv[4], lsx[4], lsy[4];
    __shared__ int lmi[4];
    if (lane == 0) { lmv[wid] = mv; lmi[wid] = mi; lsx[wid] = sx; lsy[wid] = sy; }
    __syncthreads();
    if (tid == 0) {
        for (int w = 1; w < 4; ++w) {
            if (lmv[w] > lmv[0] || (lmv[w] == lmv[0] && lmi[w] < lmi[0])) {
                lmv[0] = lmv[w];
                lmi[0] = lmi[w];
            }
            lsx[0] += lsx[w];
            lsy[0] += lsy[w];
        }
        Pmax[blk] = lmv[0];
        Pidx[blk] = lmi[0];
        Psx[blk] = lsx[0];
        Psy[blk] = lsy[0];
    }
}

// Stage 2: channel-major Zc[b][p] = (Xs+fix)*invX - Y0*invY. Each block owns one
// (b, 4K-pixel chunk); combine of the 32 partials is redundantly recomputed per
// 32-lane group (cheap). All reads/writes fully coalesced.
__global__ __launch_bounds__(256) void zprep_kernel(const float* __restrict__ Pmax,
                                                    const int* __restrict__ Pidx,
                                                    const float* __restrict__ Psx,
                                                    const float* __restrict__ Psy,
                                                    const float* __restrict__ Xs,
                                                    const float* __restrict__ Y,
                                                    float* __restrict__ Zc) {
    const int blk = blockIdx.x;
    const int b = blk >> 2, ch = blk & 3;
    const int tid = threadIdx.x;
    const int c = tid & 31;

    float mv = Pmax[b * 32 + c];
    int mi = Pidx[b * 32 + c];
    float sx = Psx[b * 32 + c];
    float sy = Psy[b * 32 + c];
#pragma unroll
    for (int off = 16; off > 0; off >>= 1) {
        float ov = __shfl_down(mv, off, 32);
        int oi = __shfl_down(mi, off, 32);
        float osx = __shfl_down(sx, off, 32);
        float osy = __shfl_down(sy, off, 32);
        if (ov > mv || (ov == mv && oi < mi)) { mv = ov; mi = oi; }
        sx += osx;
        sy += osy;
    }
    mv = __shfl(mv, 0, 32);
    mi = __shfl(mi, 0, 32);
    sx = __shfl(sx, 0, 32);
    sy = __shfl(sy, 0, 32);
    const float fa = (mv < EPSV) ? (EPSV - mv) : 0.0f;
    const int fi = mi;
    const float invX = 1.0f / (sx + fa);
    const float invY = 1.0f / sy;

    const int p0 = ch * 4096 + tid * 16;
    const float* xsb = Xs + (size_t)b * HW;
    const float* y0b = Y + (size_t)b * 3 * HW;
    float* zb = Zc + (size_t)b * HW;
#pragma unroll
    for (int q = 0; q < 4; ++q) {
        int p = p0 + q * 4;
        float4 xs = *(const float4*)(xsb + p);
        float4 y0 = *(const float4*)(y0b + p);
        if (p <= fi && fi < p + 4) {
            float* xc = (float*)&xs;
            xc[fi - p] += fa;
        }
        float4 z;
        z.x = xs.x * invX - y0.x * invY;
        z.y = xs.y * invX - y0.y * invY;
        z.z = xs.z * invX - y0.z * invY;
        z.w = xs.w * invX - y0.w * invY;
        *(float4*)(zb + p) = z;
    }
}

// Two blocks per projection; half h owns channels [4h, 4h+4). Phase 1: analytic
// ranksort builds BOTH LDS tables: rank[p] (pixel-major) and sid[k] (sorted).
// Then dpc[16] per thread precomputed once from sid. Per channel: coalesced
// streaming read of Zc[b], LDS scatter sbuf[rank[p]] = z, barrier, contiguous
// scan of sbuf + integral. No divergent global traffic anywhere.
__global__ __launch_bounds__(1024)
__attribute__((amdgpu_waves_per_eu(4, 4)))
void wproj_kernel(const float* __restrict__ proj,
                  const float* __restrict__ Zc,
                  float* __restrict__ out) {
    __shared__ unsigned short rnkT[HW];  // 32 KiB rank[pixel]
    __shared__ unsigned short sidT[HW];  // 32 KiB id[sorted pos]
    __shared__ float sbuf[HW];           // 64 KiB scatter buffer (one channel)
    __shared__ int c_t[255];
    __shared__ unsigned char e_t[255];
    __shared__ float lw[16];
    __shared__ float lred[16];

    const int jp = blockIdx.x >> 1;
    const int h = blockIdx.x & 1;
    const int tid = threadIdx.x, lane = tid & 63, wid = tid >> 6;
    float a = proj[jp];
    float b = proj[NPROJ + jp];
    float inv = 1.0f / sqrtf(a * a + b * b);
    const float an = a * inv, bn = b * inv;
    const float ap = fabsf(an), bp = fabsf(bn);
    const bool flipi = (an < 0.0f), flipj = (bn < 0.0f);

    // ---- phase 1: ranksort -> rank[] and sid[] ----
    if (bp == 0.0f) {
        for (int t = tid; t < HW; t += 1024) {
            int i2 = t >> 7, j2 = t & 127;
            int ii = flipi ? 127 - i2 : i2;
            int jj = flipj ? 127 - j2 : j2;
            int idv = ii * 128 + jj;
            sidT[t] = (unsigned short)idv;
            rnkT[idv] = (unsigned short)t;
        }
    } else {
        if (tid < 255) {
            int d = tid - 127;
            double v = (double)d * ((double)ap / (double)bp);
            double cv = ceil(v);
            e_t[tid] = (cv == v) ? 1 : 0;
            c_t[tid] = (int)fmin(fmax(cv, -128.0), 129.0);
        }
        __syncthreads();
        {
            const int j2 = tid & 127;
            const int g = tid >> 7;          // 0..7, each covers 16 rows of i2
            const int i2s = g * 16;
            const int jj = flipj ? 127 - j2 : j2;

            int wsum = 0;
#pragma unroll 8
            for (int q = 0; q < 128; ++q)
                wsum += min(max(c_t[i2s + q] + j2, 0), 128);
            int tsum = 0;
            for (int i2p = 1; i2p <= i2s; ++i2p) {
                if (e_t[i2p + 127]) {
                    int tj = j2 + c_t[i2p + 127];
                    if (tj >= 0 && tj < 128) tsum++;
                }
            }
            for (int q = 0; q < 16; ++q) {
                int i2 = i2s + q;
                if (q > 0) {
                    int dd_new = i2 + 127;
                    int dd_old = i2 - 1;
                    int cn = c_t[dd_new];
                    wsum += min(max(cn + j2, 0), 128);
                    wsum -= min(max(c_t[dd_old] + j2, 0), 128);
                    if (e_t[dd_new]) {
                        int tj = j2 + cn;
                        if (tj >= 0 && tj < 128) tsum++;
                    }
                }
                int pos = wsum + tsum;
                int ii = flipi ? 127 - i2 : i2;
                int idv = ii * 128 + jj;
                sidT[pos] = (unsigned short)idv;
                rnkT[idv] = (unsigned short)pos;
            }
        }
    }
    __syncthreads();

    // ---- preload: ranks of own 16 pixels; dpc of own 16 sorted positions ----
    const int pbase = tid * 16;
    int rnk[16];
#pragma unroll
    for (int m = 0; m < 16; ++m) rnk[m] = (int)rnkT[pbase + m];

    float dpc[16];
    {
        int id0 = (int)sidT[pbase];
        float pc_cur = (float)(id0 >> 7) * an + (float)(id0 & 127) * bn;
#pragma unroll
        for (int m = 0; m < 16; ++m) {
            int k = pbase + m;
            if (k < HW - 1) {
                int idn = (int)sidT[k + 1];
                float pc_nxt = (float)(idn >> 7) * an + (float)(idn & 127) * bn;
                dpc[m] = pc_nxt - pc_cur;
                pc_cur = pc_nxt;
            } else {
                dpc[m] = 0.0f;
            }
        }
    }

    // ---- phase 2: 4 channels, scatter -> scan -> integral ----
    float acc = 0.0f;
#pragma unroll 1
    for (int cg = 0; cg < 4; ++cg) {
        const float* zc = Zc + (size_t)(4 * h + cg) * HW + pbase;
        float zz[16];
#pragma unroll
        for (int q = 0; q < 4; ++q) {
            float4 v = *(const float4*)(zc + q * 4);
            zz[q * 4 + 0] = v.x;
            zz[q * 4 + 1] = v.y;
            zz[q * 4 + 2] = v.z;
            zz[q * 4 + 3] = v.w;
        }
#pragma unroll
        for (int m = 0; m < 16; ++m) sbuf[rnk[m]] = zz[m];
        __syncthreads();

        float pf[16];
        float run = 0.0f;
#pragma unroll
        for (int q = 0; q < 4; ++q) {
            float4 v = *(const float4*)(sbuf + pbase + q * 4);
            run += v.x; pf[q * 4 + 0] = run;
            run += v.y; pf[q * 4 + 1] = run;
            run += v.z; pf[q * 4 + 2] = run;
            run += v.w; pf[q * 4 + 3] = run;
        }
        const float tot = run;
        float ia = tot;
#pragma unroll
        for (int off = 1; off < 64; off <<= 1) {
            float ua = __shfl_up(ia, off);
            if (lane >= off) ia += ua;
        }
        if (lane == 63) lw[wid] = ia;
        __syncthreads();
        float pre = ia - tot;
#pragma unroll
        for (int w = 0; w < 16; ++w)
            if (w < wid) pre += lw[w];

#pragma unroll
        for (int m = 0; m < 16; ++m)
            acc += fabsf(pre + pf[m]) * dpc[m];
        __syncthreads();  // sbuf/lw reused next channel
    }

    // block reduce
#pragma unroll
    for (int off = 32; off > 0; off >>= 1) acc += __shfl_down(acc, off);
    if (lane == 0) lred[wid] = acc;
    __syncthreads();
    if (tid == 0) {
        float r = 0.0f;
        for (int w = 0; w < 16; ++w) r += lred[w];
        atomicAdd(out, r * (1.0f / NPROJ));
    }
}

extern "C" void kernel_launch(void* const* d_in, const int* in_sizes, int n_in,
                              void* d_out, int out_size, void* d_ws, size_t ws_size,
                              hipStream_t stream) {
    const float* X = (const float*)d_in[0];
    const float* Y = (const float*)d_in[1];
    const float* proj = (const float*)d_in[2];
    float* out = (float*)d_out;

    char* ws = (char*)d_ws;
    size_t off = 0;
    float* Xs = (float*)(ws + off);     off += (size_t)NB * HW * sizeof(float);
    float* Zc = (float*)(ws + off);     off += (size_t)NB * HW * sizeof(float);
    float* Pmax = (float*)(ws + off);   off += NB * NCH * sizeof(float);
    int* Pidx = (int*)(ws + off);       off += NB * NCH * sizeof(int);
    float* Psx = (float*)(ws + off);    off += NB * NCH * sizeof(float);
    float* Psy = (float*)(ws + off);    off += NB * NCH * sizeof(float);

    partial_kernel<<<NB * NCH, 256, 0, stream>>>(X, Y, Xs, Pmax, Pidx, Psx, Psy, out);
    zprep_kernel<<<NB * 4, 256, 0, stream>>>(Pmax, Pidx, Psx, Psy, Xs, Y, Zc);
    wproj_kernel<<<NPROJ * 2, 1024, 0, stream>>>(proj, Zc, out);
}

// Round 11
// 38.478 us; speedup vs baseline: 1.2396x; 1.2396x over previous
//
#include <hip/hip_runtime.h>
#include <hip/hip_fp16.h>
#include <math.h>

#define HW 16384
#define NPROJ 100
#define NB 8
#define NCH 32
#define CHLEN 512
#define EPSV 1e-6f

__device__ inline float4 add4(float4 a, float4 b) {
    return make_float4(a.x + b.x, a.y + b.y, a.z + b.z, a.w + b.w);
}
__device__ inline float4 sub4(float4 a, float4 b) {
    return make_float4(a.x - b.x, a.y - b.y, a.z - b.z, a.w - b.w);
}
__device__ inline float4 shfl_up4(float4 v, int off) {
    return make_float4(__shfl_up(v.x, off), __shfl_up(v.y, off),
                       __shfl_up(v.z, off), __shfl_up(v.w, off));
}
__device__ inline unsigned int packh2(float a, float b) {
    __half2 h = __floats2half2_rn(a, b);
    return *reinterpret_cast<unsigned int*>(&h);
}
__device__ inline float2 unpackh2(unsigned int w) {
    __half2 h = *reinterpret_cast<__half2*>(&w);
    return make_float2(__low2float(h), __high2float(h));
}

// Stage 1: per-(batch, chunk) partials: Xs = x0+x1+x2 (stored), sum(Xs), sum(y0),
// chunk max/argmax of x0 (first-occurrence). Block 0 zeroes the output.
__global__ __launch_bounds__(256) void partial_kernel(const float* __restrict__ X,
                                                      const float* __restrict__ Y,
                                                      float* __restrict__ Xs,
                                                      float* __restrict__ Pmax,
                                                      int* __restrict__ Pidx,
                                                      float* __restrict__ Psx,
                                                      float* __restrict__ Psy,
                                                      float* __restrict__ out) {
    const int blk = blockIdx.x;
    const int b = blk >> 5, c = blk & 31;
    const int tid = threadIdx.x, lane = tid & 63, wid = tid >> 6;
    if (blk == 0 && tid == 0) out[0] = 0.0f;  // consumed only by wproj (later kernel)
    const float* xb = X + (size_t)b * 3 * HW;
    const float* yb = Y + (size_t)b * 3 * HW;
    const int base = c * CHLEN;

    float mv = -INFINITY;
    int mi = 0;
    float sx = 0.0f, sy = 0.0f;
#pragma unroll
    for (int k = 0; k < 2; ++k) {
        int p = base + k * 256 + tid;
        float x0 = xb[p], x1 = xb[HW + p], x2 = xb[2 * HW + p], y0 = yb[p];
        float s = x0 + x1 + x2;
        Xs[(size_t)b * HW + p] = s;
        sx += s;
        sy += y0;
        if (x0 > mv) { mv = x0; mi = p; }   // strict > keeps earliest p
    }
#pragma unroll
    for (int off = 32; off > 0; off >>= 1) {
        float ov = __shfl_down(mv, off);
        int oi = __shfl_down(mi, off);
        sx += __shfl_down(sx, off);
        sy += __shfl_down(sy, off);
        if (ov > mv || (ov == mv && oi < mi)) { mv = ov; mi = oi; }
    }
    __shared__ float lmv[4], lsx[4], lsy[4];
    __shared__ int lmi[4];
    if (lane == 0) { lmv[wid] = mv; lmi[wid] = mi; lsx[wid] = sx; lsy[wid] = sy; }
    __syncthreads();
    if (tid == 0) {
        for (int w = 1; w < 4; ++w) {
            if (lmv[w] > lmv[0] || (lmv[w] == lmv[0] && lmi[w] < lmi[0])) {
                lmv[0] = lmv[w];
                lmi[0] = lmi[w];
            }
            lsx[0] += lsx[w];
            lsy[0] += lsy[w];
        }
        Pmax[blk] = lmv[0];
        Pidx[blk] = lmi[0];
        Psx[blk] = lsx[0];
        Psy[blk] = lsy[0];
    }
}

// Stage 2 (combine folded in): every block redundantly reduces the 8x32 partials,
// then builds Zh[p] = packed fp16 x8: (Xs+fix)*invX - Y0*invY, pixel-major 16B.
__global__ __launch_bounds__(256) void zprep_kernel(const float* __restrict__ Pmax,
                                                    const int* __restrict__ Pidx,
                                                    const float* __restrict__ Psx,
                                                    const float* __restrict__ Psy,
                                                    const float* __restrict__ Xs,
                                                    const float* __restrict__ Y,
                                                    uint4* __restrict__ Zh) {
    __shared__ float sInvX[8], sInvY[8], sFa[8];
    __shared__ int sFi[8];
    const int tid = threadIdx.x;
    const int c = tid & 31;
    {
        const int b = tid >> 5;
        float mv = Pmax[tid];
        int mi = Pidx[tid];
        float sx = Psx[tid];
        float sy = Psy[tid];
#pragma unroll
        for (int off = 16; off > 0; off >>= 1) {
            float ov = __shfl_down(mv, off, 32);
            int oi = __shfl_down(mi, off, 32);
            float osx = __shfl_down(sx, off, 32);
            float osy = __shfl_down(sy, off, 32);
            if (ov > mv || (ov == mv && oi < mi)) { mv = ov; mi = oi; }
            sx += osx;
            sy += osy;
        }
        if (c == 0) {
            float fa = (mv < EPSV) ? (EPSV - mv) : 0.0f;
            sFa[b] = fa;
            sFi[b] = mi;
            sInvX[b] = 1.0f / (sx + fa);
            sInvY[b] = 1.0f / sy;
        }
    }
    __syncthreads();
    const int p = blockIdx.x * 256 + tid;
    float z[8];
#pragma unroll
    for (int b = 0; b < 8; ++b) {
        float s = Xs[(size_t)b * HW + p];
        if (p == sFi[b]) s += sFa[b];
        z[b] = s * sInvX[b] - Y[(size_t)b * 3 * HW + p] * sInvY[b];
    }
    Zh[p] = make_uint4(packh2(z[0], z[1]), packh2(z[2], z[3]),
                       packh2(z[4], z[5]), packh2(z[6], z[7]));
}

// Two blocks per projection (half h owns sorted positions [h*8192,(h+1)*8192)).
// Phase 1: full analytic ranksort (duplicated per half, cheap), keep own half in
// a transposed 16KB LDS table; capture boundary id at pos 8192.
// Phase 2: ONE 16B gather per pixel (8 fp16 channels packed) into raw[8] regs;
// then 2 channel-group passes unpack from registers (static component selects),
// register prefix + wave/block scan. Cross-half carry via sum(Z)=0.
__global__ __launch_bounds__(1024)
__attribute__((amdgpu_waves_per_eu(4, 4)))
void wproj_kernel(const float* __restrict__ proj,
                  const uint4* __restrict__ Zh,
                  float* __restrict__ out) {
    __shared__ unsigned short sidT[8 * 1024];  // 16 KiB, transposed [m][tid]
    __shared__ int c_t[255];
    __shared__ unsigned char e_t[255];
    __shared__ float4 lw[16];
    __shared__ float lred[16];
    __shared__ int sBound;  // pixel id at global sorted position 8192

    const int jp = blockIdx.x >> 1;
    const int h = blockIdx.x & 1;
    const int tid = threadIdx.x, lane = tid & 63, wid = tid >> 6;
    float a = proj[jp];
    float b = proj[NPROJ + jp];
    float inv = 1.0f / sqrtf(a * a + b * b);
    const float an = a * inv, bn = b * inv;
    const float ap = fabsf(an), bp = fabsf(bn);
    const bool flipi = (an < 0.0f), flipj = (bn < 0.0f);

    // ---- phase 1: ranksort; keep own half in transposed LDS table ----
    if (bp == 0.0f) {
        for (int t = tid; t < HW; t += 1024) {
            int i2 = t >> 7, j2 = t & 127;
            int ii = flipi ? 127 - i2 : i2;
            int jj = flipj ? 127 - j2 : j2;
            int idv = ii * 128 + jj;
            if (t == 8192) sBound = idv;
            int q = t - (h << 13);
            if ((unsigned)q < 8192u)
                sidT[(q & 7) * 1024 + (q >> 3)] = (unsigned short)idv;
        }
    } else {
        if (tid < 255) {
            int d = tid - 127;
            double v = (double)d * ((double)ap / (double)bp);
            double cv = ceil(v);
            e_t[tid] = (cv == v) ? 1 : 0;
            c_t[tid] = (int)fmin(fmax(cv, -128.0), 129.0);
        }
        __syncthreads();
        {
            const int j2 = tid & 127;
            const int g = tid >> 7;          // 0..7, each covers 16 rows of i2
            const int i2s = g * 16;
            const int jj = flipj ? 127 - j2 : j2;

            int wsum = 0;
#pragma unroll 8
            for (int q = 0; q < 128; ++q)
                wsum += min(max(c_t[i2s + q] + j2, 0), 128);
            int tsum = 0;
            for (int i2p = 1; i2p <= i2s; ++i2p) {
                if (e_t[i2p + 127]) {
                    int tj = j2 + c_t[i2p + 127];
                    if (tj >= 0 && tj < 128) tsum++;
                }
            }
            for (int q = 0; q < 16; ++q) {
                int i2 = i2s + q;
                if (q > 0) {
                    int dd_new = i2 + 127;
                    int dd_old = i2 - 1;
                    int cn = c_t[dd_new];
                    wsum += min(max(cn + j2, 0), 128);
                    wsum -= min(max(c_t[dd_old] + j2, 0), 128);
                    if (e_t[dd_new]) {
                        int tj = j2 + cn;
                        if (tj >= 0 && tj < 128) tsum++;
                    }
                }
                int pos = wsum + tsum;
                int ii = flipi ? 127 - i2 : i2;
                int idv = ii * 128 + jj;
                if (pos == 8192) sBound = idv;
                int ql = pos - (h << 13);
                if ((unsigned)ql < 8192u)
                    sidT[(ql & 7) * 1024 + (ql >> 3)] = (unsigned short)idv;
            }
        }
    }
    __syncthreads();

    // ---- phase 2: thread owns local positions [8*tid, 8*tid+7] ----
    int ids[9];
#pragma unroll
    for (int m = 0; m < 8; ++m) ids[m] = (int)sidT[m * 1024 + tid];
    ids[8] = (tid < 1023) ? (int)sidT[tid + 1]
                          : ((h == 0) ? sBound : ids[7]);  // h==1 tail unused

    // single 16B gather per pixel: all 8 channels packed fp16
    uint4 raw[8];
#pragma unroll
    for (int m = 0; m < 8; ++m) raw[m] = Zh[ids[m]];

    float acc = 0.0f;
#pragma unroll 1
    for (int cg = 0; cg < 2; ++cg) {
        float4 zv[8];
#pragma unroll
        for (int m = 0; m < 8; ++m) {
            unsigned int d0 = (cg == 0) ? raw[m].x : raw[m].z;
            unsigned int d1 = (cg == 0) ? raw[m].y : raw[m].w;
            float2 f0 = unpackh2(d0);
            float2 f1 = unpackh2(d1);
            zv[m] = make_float4(f0.x, f0.y, f1.x, f1.y);
        }
#pragma unroll
        for (int m = 1; m < 8; ++m) zv[m] = add4(zv[m], zv[m - 1]);
        const float4 tot = zv[7];

        float4 ia = tot;
#pragma unroll
        for (int off = 1; off < 64; off <<= 1) {
            float4 ua = shfl_up4(ia, off);
            if (lane >= off) ia = add4(ia, ua);
        }
        if (lane == 63) lw[wid] = ia;
        __syncthreads();

        float4 pre = sub4(ia, tot);  // exclusive within wave
        float4 T = make_float4(0, 0, 0, 0);
#pragma unroll
        for (int w = 0; w < 16; ++w) {
            if (w < wid) pre = add4(pre, lw[w]);
            T = add4(T, lw[w]);
        }
        if (h == 1) pre = sub4(pre, T);  // carry = total(half0) = -total(half1)

        float pc_cur = (float)(ids[0] >> 7) * an + (float)(ids[0] & 127) * bn;
#pragma unroll
        for (int m = 0; m < 8; ++m) {
            int idn = ids[m + 1];
            float pc_nxt = (float)(idn >> 7) * an + (float)(idn & 127) * bn;
            float4 cx = add4(pre, zv[m]);
            float s4 = fabsf(cx.x) + fabsf(cx.y) + fabsf(cx.z) + fabsf(cx.w);
            int gk = (h << 13) + tid * 8 + m;
            if (gk < HW - 1) acc += s4 * (pc_nxt - pc_cur);
            pc_cur = pc_nxt;
        }
        __syncthreads();  // protect lw reuse in next pass
    }

    // block reduce
#pragma unroll
    for (int off = 32; off > 0; off >>= 1) acc += __shfl_down(acc, off);
    if (lane == 0) lred[wid] = acc;
    __syncthreads();
    if (tid == 0) {
        float r = 0.0f;
        for (int w = 0; w < 16; ++w) r += lred[w];
        atomicAdd(out, r * (1.0f / NPROJ));
    }
}

extern "C" void kernel_launch(void* const* d_in, const int* in_sizes, int n_in,
                              void* d_out, int out_size, void* d_ws, size_t ws_size,
                              hipStream_t stream) {
    const float* X = (const float*)d_in[0];
    const float* Y = (const float*)d_in[1];
    const float* proj = (const float*)d_in[2];
    float* out = (float*)d_out;

    char* ws = (char*)d_ws;
    size_t off = 0;
    float* Xs = (float*)(ws + off);     off += (size_t)NB * HW * sizeof(float);
    uint4* Zh = (uint4*)(ws + off);     off += (size_t)HW * sizeof(uint4);
    float* Pmax = (float*)(ws + off);   off += NB * NCH * sizeof(float);
    int* Pidx = (int*)(ws + off);       off += NB * NCH * sizeof(int);
    float* Psx = (float*)(ws + off);    off += NB * NCH * sizeof(float);
    float* Psy = (float*)(ws + off);    off += NB * NCH * sizeof(float);

    partial_kernel<<<NB * NCH, 256, 0, stream>>>(X, Y, Xs, Pmax, Pidx, Psx, Psy, out);
    zprep_kernel<<<HW / 256, 256, 0, stream>>>(Pmax, Pidx, Psx, Psy, Xs, Y, Zh);
    wproj_kernel<<<NPROJ * 2, 1024, 0, stream>>>(proj, Zh, out);
}